// Round 1
// baseline (760.122 us; speedup 1.0000x reference)
//
#include <hip/hip_runtime.h>
#include <hip/hip_bf16.h>

// Problem constants
#define IN_F   4096
#define OUT_F  4096
#define RTOT   128
#define NE     8
#define RP     16
#define NROWS  8192
#define KC     (IN_F + RTOT)   // 4224 concatenated K
#define NG     144             // AG rows: 128 loraA + 8 gate + 8 zero pad
#define SCALING 0.125f         // ALPHA / R = 16/128

typedef __attribute__((ext_vector_type(8))) short bf16x8;   // 8 bf16 (4 VGPRs)
typedef __attribute__((ext_vector_type(4))) float f32x4;    // 4 fp32 acc

// async global -> LDS, 16 B per lane (global_load_lds_dwordx4)
__device__ __forceinline__ void gl_lds16(const __hip_bfloat16* g, __hip_bfloat16* l) {
    __builtin_amdgcn_global_load_lds(
        (const __attribute__((address_space(1))) unsigned int*)g,
        (__attribute__((address_space(3))) unsigned int*)l, 16, 0, 0);
}

// ---------------- prep: Wcat[o][0:4096]=W0[o], Wcat[o][4096+e*16+r]=B[e][o][r] ----------------
__global__ void k_prep_wcat(const float* __restrict__ W0, const float* __restrict__ B,
                            __hip_bfloat16* __restrict__ Wcat) {
    int idx = blockIdx.x * 256 + threadIdx.x;        // 4096*4224 total, exact grid
    int o = idx / KC;
    int c = idx - o * KC;
    float v;
    if (c < IN_F) {
        v = W0[o * IN_F + c];
    } else {
        int k = c - IN_F;
        int e = k >> 4, r = k & 15;
        v = B[(e * OUT_F + o) * RP + r];
    }
    Wcat[idx] = __float2bfloat16(v);
}

// ---------------- prep: Xcat[n][0:4096] = bf16(x[n]) (hg part filled later) ----------------
__global__ void k_xconv(const float4* __restrict__ x4, __hip_bfloat16* __restrict__ Xcat) {
    int idx = blockIdx.x * 256 + threadIdx.x;        // 8192*1024 float4 groups
    int n  = idx >> 10;
    int c4 = idx & 1023;
    float4 v = x4[idx];
    union { ushort4 u4; __hip_bfloat16 h[4]; } p;
    p.h[0] = __float2bfloat16(v.x);
    p.h[1] = __float2bfloat16(v.y);
    p.h[2] = __float2bfloat16(v.z);
    p.h[3] = __float2bfloat16(v.w);
    *(ushort4*)(&Xcat[(size_t)n * KC + (c4 << 2)]) = p.u4;
}

// ---------------- prep: AG rows 0..127 = A (flattened e*16+r), 128..135 = Wg, 136..143 = 0 ----
__global__ void k_prep_ag(const float* __restrict__ A, const float* __restrict__ Wg,
                          __hip_bfloat16* __restrict__ AG) {
    int idx = blockIdx.x * 256 + threadIdx.x;        // 144*4096 total
    int row = idx >> 12;
    int d   = idx & 4095;
    float v = 0.0f;
    if (row < RTOT)      v = A[idx];                 // A flat [e][r][d] == row-major [128][4096]
    else if (row < 136)  v = Wg[(row - RTOT) * IN_F + d];
    AG[idx] = __float2bfloat16(v);
}

// ---------------- H[8192][144] = Xcat[:, :4096] @ AG^T (bf16 MFMA) ----------------
__global__ __launch_bounds__(256) void k_hgemm(const __hip_bfloat16* __restrict__ Xcat,
                                               const __hip_bfloat16* __restrict__ AG,
                                               float* __restrict__ H) {
    __shared__ __hip_bfloat16 sX[128 * 32];
    __shared__ __hip_bfloat16 sG[NG * 32];
    const int tid  = threadIdx.x;
    const int lane = tid & 63;
    const int w    = tid >> 6;          // wave handles rows w*32 .. w*32+31
    const int quad = lane >> 4;
    const int l16  = lane & 15;
    const int m0   = blockIdx.x * 128;

    f32x4 acc[2][9];
    for (int i = 0; i < 2; ++i)
        for (int j = 0; j < 9; ++j)
            acc[i][j] = (f32x4){0.f, 0.f, 0.f, 0.f};

    const int sr = tid >> 2, sk = (tid & 3) << 3;   // staging slot -> (row, k-offset)

    for (int kt = 0; kt < IN_F; kt += 32) {
        __syncthreads();
        // X tile: 128x32 = 512 slots of 8 elems, 2 rounds
        gl_lds16(&Xcat[(size_t)(m0 + sr) * KC + kt + sk],        &sX[tid * 8]);
        gl_lds16(&Xcat[(size_t)(m0 + 64 + sr) * KC + kt + sk],   &sX[(tid + 256) * 8]);
        // AG tile: 144x32 = 576 slots, 2 full rounds + 64
        gl_lds16(&AG[(size_t)sr * IN_F + kt + sk],               &sG[tid * 8]);
        gl_lds16(&AG[(size_t)(64 + sr) * IN_F + kt + sk],        &sG[(tid + 256) * 8]);
        if (tid < 64)
            gl_lds16(&AG[(size_t)(128 + sr) * IN_F + kt + sk],   &sG[(tid + 512) * 8]);
        __syncthreads();

        bf16x8 a[2], b[9];
#pragma unroll
        for (int ti = 0; ti < 2; ++ti)
            a[ti] = *(const bf16x8*)(&sX[(w * 32 + ti * 16 + l16) * 32 + quad * 8]);
#pragma unroll
        for (int tj = 0; tj < 9; ++tj)
            b[tj] = *(const bf16x8*)(&sG[(tj * 16 + l16) * 32 + quad * 8]);
#pragma unroll
        for (int ti = 0; ti < 2; ++ti)
#pragma unroll
            for (int tj = 0; tj < 9; ++tj)
                acc[ti][tj] = __builtin_amdgcn_mfma_f32_16x16x32_bf16(a[ti], b[tj], acc[ti][tj], 0, 0, 0);
    }

#pragma unroll
    for (int ti = 0; ti < 2; ++ti)
#pragma unroll
        for (int tj = 0; tj < 9; ++tj) {
            int col = tj * 16 + l16;
#pragma unroll
            for (int i = 0; i < 4; ++i) {
                int row = m0 + w * 32 + ti * 16 + quad * 4 + i;
                H[(size_t)row * NG + col] = acc[ti][tj][i];
            }
        }
}

// ---------------- gate softmax + scaled hg write into Xcat[:, 4096:] ----------------
__global__ void k_gate(const float* __restrict__ H, __hip_bfloat16* __restrict__ Xcat) {
    int n = blockIdx.x * 256 + threadIdx.x;          // 8192 rows
    const float* h = &H[(size_t)n * NG];
    float lg[NE];
    float mx = -1e30f;
#pragma unroll
    for (int e = 0; e < NE; ++e) { lg[e] = h[128 + e]; mx = fmaxf(mx, lg[e]); }
    float s = 0.f;
#pragma unroll
    for (int e = 0; e < NE; ++e) { lg[e] = __expf(lg[e] - mx); s += lg[e]; }
    float inv = SCALING / s;
    __hip_bfloat16* dst = &Xcat[(size_t)n * KC + IN_F];
    for (int k = 0; k < RTOT; ++k)
        dst[k] = __float2bfloat16(h[k] * lg[k >> 4] * inv);
}

// ---------------- out[8192][4096] = Xcat @ Wcat^T (K=4224, bf16 MFMA, m97 structure) ----------
__global__ __launch_bounds__(256) void k_gemm(const __hip_bfloat16* __restrict__ Xcat,
                                              const __hip_bfloat16* __restrict__ Wcat,
                                              float* __restrict__ out) {
    __shared__ __hip_bfloat16 sA[128 * 32];
    __shared__ __hip_bfloat16 sB[128 * 32];
    const int tid  = threadIdx.x;
    const int lane = tid & 63;
    const int w    = tid >> 6;
    const int wm   = w >> 1, wn = w & 1;  // 2x2 waves, each 64x64
    const int quad = lane >> 4;
    const int l16  = lane & 15;
    const int m0   = blockIdx.y * 128;
    const int n0   = blockIdx.x * 128;

    f32x4 acc[4][4];
#pragma unroll
    for (int i = 0; i < 4; ++i)
#pragma unroll
        for (int j = 0; j < 4; ++j)
            acc[i][j] = (f32x4){0.f, 0.f, 0.f, 0.f};

    const int sr = tid >> 2, sk = (tid & 3) << 3;
    const __hip_bfloat16* gA0 = &Xcat[(size_t)(m0 + sr) * KC + sk];
    const __hip_bfloat16* gA1 = &Xcat[(size_t)(m0 + 64 + sr) * KC + sk];
    const __hip_bfloat16* gB0 = &Wcat[(size_t)(n0 + sr) * KC + sk];
    const __hip_bfloat16* gB1 = &Wcat[(size_t)(n0 + 64 + sr) * KC + sk];

    for (int kt = 0; kt < KC; kt += 32) {
        __syncthreads();
        gl_lds16(gA0 + kt, &sA[tid * 8]);
        gl_lds16(gA1 + kt, &sA[(tid + 256) * 8]);
        gl_lds16(gB0 + kt, &sB[tid * 8]);
        gl_lds16(gB1 + kt, &sB[(tid + 256) * 8]);
        __syncthreads();

        bf16x8 a[4], b[4];
#pragma unroll
        for (int t = 0; t < 4; ++t) {
            a[t] = *(const bf16x8*)(&sA[(wm * 64 + t * 16 + l16) * 32 + quad * 8]);
            b[t] = *(const bf16x8*)(&sB[(wn * 64 + t * 16 + l16) * 32 + quad * 8]);
        }
#pragma unroll
        for (int ti = 0; ti < 4; ++ti)
#pragma unroll
            for (int tj = 0; tj < 4; ++tj)
                acc[ti][tj] = __builtin_amdgcn_mfma_f32_16x16x32_bf16(a[ti], b[tj], acc[ti][tj], 0, 0, 0);
    }

#pragma unroll
    for (int ti = 0; ti < 4; ++ti)
#pragma unroll
        for (int tj = 0; tj < 4; ++tj) {
            int col = n0 + wn * 64 + tj * 16 + l16;
#pragma unroll
            for (int i = 0; i < 4; ++i) {
                int row = m0 + wm * 64 + ti * 16 + quad * 4 + i;
                out[(size_t)row * OUT_F + col] = acc[ti][tj][i];
            }
        }
}

extern "C" void kernel_launch(void* const* d_in, const int* in_sizes, int n_in,
                              void* d_out, int out_size, void* d_ws, size_t ws_size,
                              hipStream_t stream) {
    const float* x  = (const float*)d_in[0];   // [8192, 4096]
    const float* W0 = (const float*)d_in[1];   // [4096, 4096]
    const float* Wg = (const float*)d_in[2];   // [8, 4096]
    const float* A  = (const float*)d_in[3];   // [8, 16, 4096]
    const float* B  = (const float*)d_in[4];   // [8, 4096, 16]
    float* out = (float*)d_out;

    char* ws = (char*)d_ws;
    size_t off = 0;
    __hip_bfloat16* Xcat = (__hip_bfloat16*)(ws + off); off += (size_t)NROWS * KC * 2;   // 69.2 MB
    __hip_bfloat16* Wcat = (__hip_bfloat16*)(ws + off); off += (size_t)OUT_F * KC * 2;   // 34.6 MB
    __hip_bfloat16* AG   = (__hip_bfloat16*)(ws + off); off += (size_t)NG * IN_F * 2;    // 1.2 MB
    float*          H    = (float*)(ws + off);          off += (size_t)NROWS * NG * 4;   // 4.7 MB

    k_prep_wcat<<<(OUT_F * KC) / 256, 256, 0, stream>>>(W0, B, Wcat);
    k_xconv<<<(NROWS * (IN_F / 4)) / 256, 256, 0, stream>>>((const float4*)x, Xcat);
    k_prep_ag<<<(NG * IN_F) / 256, 256, 0, stream>>>(A, Wg, AG);
    k_hgemm<<<NROWS / 128, 256, 0, stream>>>(Xcat, AG, H);
    k_gate<<<NROWS / 256, 256, 0, stream>>>(H, Xcat);
    k_gemm<<<dim3(OUT_F / 128, NROWS / 128), 256, 0, stream>>>(Xcat, Wcat, out);
}

// Round 3
// 682.856 us; speedup vs baseline: 1.1132x; 1.1132x over previous
//
#include <hip/hip_runtime.h>
#include <hip/hip_bf16.h>

// Problem constants
#define IN_F   4096
#define OUT_F  4096
#define RTOT   128
#define NE     8
#define RP     16
#define NROWS  8192
#define KC     (IN_F + RTOT)   // 4224 concatenated K
#define NG     144             // AG rows: 128 loraA + 8 gate + 8 zero pad
#define SCALING 0.125f         // ALPHA / R = 16/128
#define KSPLIT 8               // hgemm K-split

typedef __attribute__((ext_vector_type(8))) short bf16x8;   // 8 bf16 (4 VGPRs)
typedef __attribute__((ext_vector_type(4))) float f32x4;    // 4 fp32 acc

// async global -> LDS, 16 B per lane (global_load_lds_dwordx4)
__device__ __forceinline__ void gl_lds16(const __hip_bfloat16* g, __hip_bfloat16* l) {
    __builtin_amdgcn_global_load_lds(
        (const __attribute__((address_space(1))) unsigned int*)g,
        (__attribute__((address_space(3))) unsigned int*)l, 16, 0, 0);
}

union bf8pack { bf16x8 v; __hip_bfloat16 h[8]; };
union bf4pack { ushort4 u; __hip_bfloat16 h[4]; };

// ---------------- fused prep ----------------
// region A [0, 16896):     Wcat[o][0:4096]=W0, Wcat[o][4096+e*16+r]=B[e][o][r]  (4/thread)
// region B [16896, 17472): AG rows 0..127=A, 128..135=Wg, 136..143=0            (4/thread)
// region C [17472, 33856): Xcat[:, :4096] = bf16(x)                             (8/thread)
// region D [33856, 35008): H = 0                                                (4/thread)
#define PREP_GRID 35008
__global__ void k_prep(const float* __restrict__ W0, const float* __restrict__ B,
                       const float* __restrict__ A, const float* __restrict__ Wg,
                       const float* __restrict__ x,
                       __hip_bfloat16* __restrict__ Wcat, __hip_bfloat16* __restrict__ AG,
                       __hip_bfloat16* __restrict__ Xcat, float* __restrict__ H) {
    int bid = blockIdx.x, tid = threadIdx.x;
    if (bid < 16896) {
        int i4 = (bid * 256 + tid) * 4;                // element idx into Wcat
        int o = i4 / KC;
        int c = i4 - o * KC;
        float4 v;
        if (c < IN_F) v = *(const float4*)&W0[(size_t)o * IN_F + c];
        else {
            int k = c - IN_F, e = k >> 4, r = k & 15;  // r in {0,4,8,12}
            v = *(const float4*)&B[(size_t)((e * OUT_F + o) << 4) + r];
        }
        bf4pack p;
        p.h[0] = __float2bfloat16(v.x); p.h[1] = __float2bfloat16(v.y);
        p.h[2] = __float2bfloat16(v.z); p.h[3] = __float2bfloat16(v.w);
        *(ushort4*)&Wcat[i4] = p.u;
    } else if (bid < 17472) {
        int j4 = ((bid - 16896) * 256 + tid) * 4;
        int row = j4 >> 12, d = j4 & 4095;
        float4 v = {0.f, 0.f, 0.f, 0.f};
        if (row < RTOT)      v = *(const float4*)&A[j4];
        else if (row < 136)  v = *(const float4*)&Wg[((row - RTOT) << 12) + d];
        bf4pack p;
        p.h[0] = __float2bfloat16(v.x); p.h[1] = __float2bfloat16(v.y);
        p.h[2] = __float2bfloat16(v.z); p.h[3] = __float2bfloat16(v.w);
        *(ushort4*)&AG[j4] = p.u;
    } else if (bid < 33856) {
        int t = (bid - 17472) * 256 + tid;             // 8 elems/thread, 8192*512 threads
        int n = t >> 9, c8 = t & 511;
        const float4* src = (const float4*)&x[((size_t)n << 12) + (c8 << 3)];
        float4 v0 = src[0], v1 = src[1];
        bf8pack p;
        p.h[0] = __float2bfloat16(v0.x); p.h[1] = __float2bfloat16(v0.y);
        p.h[2] = __float2bfloat16(v0.z); p.h[3] = __float2bfloat16(v0.w);
        p.h[4] = __float2bfloat16(v1.x); p.h[5] = __float2bfloat16(v1.y);
        p.h[6] = __float2bfloat16(v1.z); p.h[7] = __float2bfloat16(v1.w);
        *(bf16x8*)&Xcat[(size_t)n * KC + (c8 << 3)] = p.v;
    } else {
        int t = (bid - 33856) * 256 + tid;             // 294912 float4 of H
        ((float4*)H)[t] = (float4){0.f, 0.f, 0.f, 0.f};
    }
}

// ---------------- H[8192][144] += Xcat[:, kchunk] @ AG^T[kchunk] (split-K, atomics) ----------
__global__ __launch_bounds__(256) void k_hgemm(const __hip_bfloat16* __restrict__ Xcat,
                                               const __hip_bfloat16* __restrict__ AG,
                                               float* __restrict__ H) {
    __shared__ __hip_bfloat16 sX[128 * 32];
    __shared__ __hip_bfloat16 sG[NG * 32];
    const int tid  = threadIdx.x;
    const int lane = tid & 63;
    const int w    = tid >> 6;          // wave handles rows w*32 .. w*32+31
    const int quad = lane >> 4;
    const int l16  = lane & 15;
    const int m0   = blockIdx.x * 128;
    const int kbeg = blockIdx.y * (IN_F / KSPLIT);   // 512-wide K chunk

    f32x4 acc[2][9];
    for (int i = 0; i < 2; ++i)
        for (int j = 0; j < 9; ++j)
            acc[i][j] = (f32x4){0.f, 0.f, 0.f, 0.f};

    const int sr = tid >> 2;
    const int sk2 = (((tid & 3) ^ ((sr >> 1) & 3)) << 3);   // XOR chunk swizzle
    const int qq  = quad ^ ((l16 >> 1) & 3);                // reader swizzle (lane const)

    for (int kt = kbeg; kt < kbeg + IN_F / KSPLIT; kt += 32) {
        __syncthreads();
        gl_lds16(&Xcat[(size_t)(m0 + sr) * KC + kt + sk2],      &sX[tid * 8]);
        gl_lds16(&Xcat[(size_t)(m0 + 64 + sr) * KC + kt + sk2], &sX[(tid + 256) * 8]);
        gl_lds16(&AG[(size_t)sr * IN_F + kt + sk2],             &sG[tid * 8]);
        gl_lds16(&AG[(size_t)(64 + sr) * IN_F + kt + sk2],      &sG[(tid + 256) * 8]);
        if (tid < 64)
            gl_lds16(&AG[(size_t)(128 + sr) * IN_F + kt + sk2], &sG[(tid + 512) * 8]);
        __syncthreads();

        bf16x8 a[2], b[9];
#pragma unroll
        for (int ti = 0; ti < 2; ++ti)
            a[ti] = *(const bf16x8*)(&sX[(w * 32 + ti * 16 + l16) * 32 + qq * 8]);
#pragma unroll
        for (int tj = 0; tj < 9; ++tj)
            b[tj] = *(const bf16x8*)(&sG[(tj * 16 + l16) * 32 + qq * 8]);
#pragma unroll
        for (int ti = 0; ti < 2; ++ti)
#pragma unroll
            for (int tj = 0; tj < 9; ++tj)
                acc[ti][tj] = __builtin_amdgcn_mfma_f32_16x16x32_bf16(a[ti], b[tj], acc[ti][tj], 0, 0, 0);
    }

#pragma unroll
    for (int ti = 0; ti < 2; ++ti)
#pragma unroll
        for (int tj = 0; tj < 9; ++tj) {
            int col = tj * 16 + l16;
#pragma unroll
            for (int i = 0; i < 4; ++i) {
                int row = m0 + w * 32 + ti * 16 + quad * 4 + i;
                atomicAdd(&H[(size_t)row * NG + col], acc[ti][tj][i]);
            }
        }
}

// ---------------- gate softmax + scaled hg into Xcat[:, 4096:] (16 thr/row) ----------------
__global__ void k_gate(const float* __restrict__ H, __hip_bfloat16* __restrict__ Xcat) {
    int id = blockIdx.x * 256 + threadIdx.x;         // 8192*16 threads
    int n = id >> 4, k8 = id & 15;
    const float* h = &H[(size_t)n * NG];
    float4 g0 = *(const float4*)&h[128];
    float4 g1 = *(const float4*)&h[132];
    float lg[NE] = {g0.x, g0.y, g0.z, g0.w, g1.x, g1.y, g1.z, g1.w};
    float mx = lg[0];
#pragma unroll
    for (int e = 1; e < NE; ++e) mx = fmaxf(mx, lg[e]);
    float s = 0.f;
#pragma unroll
    for (int e = 0; e < NE; ++e) { lg[e] = __expf(lg[e] - mx); s += lg[e]; }
    float inv = SCALING / s;
    int e = k8 >> 1;                                 // expert for this 8-col chunk
    float ge = 0.f;
#pragma unroll
    for (int e2 = 0; e2 < NE; ++e2) if (e2 == e) ge = lg[e2];
    ge *= inv;
    float4 h0 = *(const float4*)&h[k8 * 8];
    float4 h1 = *(const float4*)&h[k8 * 8 + 4];
    bf8pack p;
    p.h[0] = __float2bfloat16(h0.x * ge); p.h[1] = __float2bfloat16(h0.y * ge);
    p.h[2] = __float2bfloat16(h0.z * ge); p.h[3] = __float2bfloat16(h0.w * ge);
    p.h[4] = __float2bfloat16(h1.x * ge); p.h[5] = __float2bfloat16(h1.y * ge);
    p.h[6] = __float2bfloat16(h1.z * ge); p.h[7] = __float2bfloat16(h1.w * ge);
    *(bf16x8*)&Xcat[(size_t)n * KC + IN_F + k8 * 8] = p.v;
}

// ---------------- out[8192][4096] = Xcat @ Wcat^T (K=4224, swizzled m97 structure) ----------
__global__ __launch_bounds__(256) void k_gemm(const __hip_bfloat16* __restrict__ Xcat,
                                              const __hip_bfloat16* __restrict__ Wcat,
                                              float* __restrict__ out) {
    __shared__ __hip_bfloat16 sA[128 * 32];
    __shared__ __hip_bfloat16 sB[128 * 32];
    const int tid  = threadIdx.x;
    const int lane = tid & 63;
    const int w    = tid >> 6;
    const int wm   = w >> 1, wn = w & 1;  // 2x2 waves, each 64x64
    const int quad = lane >> 4;
    const int l16  = lane & 15;
    const int m0   = blockIdx.y * 128;
    const int n0   = blockIdx.x * 128;

    f32x4 acc[4][4];
#pragma unroll
    for (int i = 0; i < 4; ++i)
#pragma unroll
        for (int j = 0; j < 4; ++j)
            acc[i][j] = (f32x4){0.f, 0.f, 0.f, 0.f};

    const int sr  = tid >> 2;
    const int sk2 = (((tid & 3) ^ ((sr >> 1) & 3)) << 3);   // XOR chunk swizzle
    const int qq  = quad ^ ((l16 >> 1) & 3);                // reader swizzle
    const __hip_bfloat16* gA0 = &Xcat[(size_t)(m0 + sr) * KC + sk2];
    const __hip_bfloat16* gA1 = &Xcat[(size_t)(m0 + 64 + sr) * KC + sk2];
    const __hip_bfloat16* gB0 = &Wcat[(size_t)(n0 + sr) * KC + sk2];
    const __hip_bfloat16* gB1 = &Wcat[(size_t)(n0 + 64 + sr) * KC + sk2];

    for (int kt = 0; kt < KC; kt += 32) {
        __syncthreads();
        gl_lds16(gA0 + kt, &sA[tid * 8]);
        gl_lds16(gA1 + kt, &sA[(tid + 256) * 8]);
        gl_lds16(gB0 + kt, &sB[tid * 8]);
        gl_lds16(gB1 + kt, &sB[(tid + 256) * 8]);
        __syncthreads();

        bf16x8 a[4], b[4];
#pragma unroll
        for (int t = 0; t < 4; ++t) {
            a[t] = *(const bf16x8*)(&sA[(wm * 64 + t * 16 + l16) * 32 + qq * 8]);
            b[t] = *(const bf16x8*)(&sB[(wn * 64 + t * 16 + l16) * 32 + qq * 8]);
        }
#pragma unroll
        for (int ti = 0; ti < 4; ++ti)
#pragma unroll
            for (int tj = 0; tj < 4; ++tj)
                acc[ti][tj] = __builtin_amdgcn_mfma_f32_16x16x32_bf16(a[ti], b[tj], acc[ti][tj], 0, 0, 0);
    }

#pragma unroll
    for (int ti = 0; ti < 4; ++ti)
#pragma unroll
        for (int tj = 0; tj < 4; ++tj) {
            int col = n0 + wn * 64 + tj * 16 + l16;
#pragma unroll
            for (int i = 0; i < 4; ++i) {
                int row = m0 + wm * 64 + ti * 16 + quad * 4 + i;
                out[(size_t)row * OUT_F + col] = acc[ti][tj][i];
            }
        }
}

extern "C" void kernel_launch(void* const* d_in, const int* in_sizes, int n_in,
                              void* d_out, int out_size, void* d_ws, size_t ws_size,
                              hipStream_t stream) {
    const float* x  = (const float*)d_in[0];   // [8192, 4096]
    const float* W0 = (const float*)d_in[1];   // [4096, 4096]
    const float* Wg = (const float*)d_in[2];   // [8, 4096]
    const float* A  = (const float*)d_in[3];   // [8, 16, 4096]
    const float* B  = (const float*)d_in[4];   // [8, 4096, 16]
    float* out = (float*)d_out;

    char* ws = (char*)d_ws;
    size_t off = 0;
    __hip_bfloat16* Xcat = (__hip_bfloat16*)(ws + off); off += (size_t)NROWS * KC * 2;   // 69.2 MB
    __hip_bfloat16* Wcat = (__hip_bfloat16*)(ws + off); off += (size_t)OUT_F * KC * 2;   // 34.6 MB
    __hip_bfloat16* AG   = (__hip_bfloat16*)(ws + off); off += (size_t)NG * IN_F * 2;    // 1.2 MB
    float*          H    = (float*)(ws + off);          off += (size_t)NROWS * NG * 4;   // 4.7 MB

    k_prep<<<PREP_GRID, 256, 0, stream>>>(W0, B, A, Wg, x, Wcat, AG, Xcat, H);
    k_hgemm<<<dim3(NROWS / 128, KSPLIT), 256, 0, stream>>>(Xcat, AG, H);
    k_gate<<<(NROWS * 16) / 256, 256, 0, stream>>>(H, Xcat);
    k_gemm<<<dim3(OUT_F / 128, NROWS / 128), 256, 0, stream>>>(Xcat, Wcat, out);
}

// Round 4
// 561.253 us; speedup vs baseline: 1.3543x; 1.2167x over previous
//
#include <hip/hip_runtime.h>
#include <hip/hip_bf16.h>

// Problem constants
#define IN_F   4096
#define OUT_F  4096
#define RTOT   128
#define NE     8
#define RP     16
#define NROWS  8192
#define KC     (IN_F + RTOT)   // 4224 concatenated K
#define NG     144             // AG rows: 128 loraA + 8 gate + 8 zero pad
#define SCALING 0.125f         // ALPHA / R = 16/128
#define KSPLIT 4               // hgemm K-split (slice-H, no atomics)

typedef __attribute__((ext_vector_type(8))) short bf16x8;   // 8 bf16 (4 VGPRs)
typedef __attribute__((ext_vector_type(4))) float f32x4;    // 4 fp32 acc

// async global -> LDS, 16 B per lane (global_load_lds_dwordx4)
__device__ __forceinline__ void gl_lds16(const __hip_bfloat16* g, __hip_bfloat16* l) {
    __builtin_amdgcn_global_load_lds(
        (const __attribute__((address_space(1))) unsigned int*)g,
        (__attribute__((address_space(3))) unsigned int*)l, 16, 0, 0);
}

union bf8pack { bf16x8 v; __hip_bfloat16 h[8]; };
union bf4pack { ushort4 u; __hip_bfloat16 h[4]; };

// ---------------- fused prep ----------------
// region A [0, 16896):     Wcat[o][0:4096]=W0, Wcat[o][4096+e*16+r]=B[e][o][r]  (4/thread)
// region B [16896, 17472): AG rows 0..127=A, 128..135=Wg, 136..143=0            (4/thread)
// region C [17472, 33856): Xcat[:, :4096] = bf16(x)                             (8/thread)
#define PREP_GRID 33856
__global__ void k_prep(const float* __restrict__ W0, const float* __restrict__ B,
                       const float* __restrict__ A, const float* __restrict__ Wg,
                       const float* __restrict__ x,
                       __hip_bfloat16* __restrict__ Wcat, __hip_bfloat16* __restrict__ AG,
                       __hip_bfloat16* __restrict__ Xcat) {
    int bid = blockIdx.x, tid = threadIdx.x;
    if (bid < 16896) {
        int i4 = (bid * 256 + tid) * 4;                // element idx into Wcat
        int o = i4 / KC;
        int c = i4 - o * KC;
        float4 v;
        if (c < IN_F) v = *(const float4*)&W0[(size_t)o * IN_F + c];
        else {
            int k = c - IN_F, e = k >> 4, r = k & 15;  // r in {0,4,8,12}
            v = *(const float4*)&B[(size_t)((e * OUT_F + o) << 4) + r];
        }
        bf4pack p;
        p.h[0] = __float2bfloat16(v.x); p.h[1] = __float2bfloat16(v.y);
        p.h[2] = __float2bfloat16(v.z); p.h[3] = __float2bfloat16(v.w);
        *(ushort4*)&Wcat[i4] = p.u;
    } else if (bid < 17472) {
        int j4 = ((bid - 16896) * 256 + tid) * 4;
        int row = j4 >> 12, d = j4 & 4095;
        float4 v = {0.f, 0.f, 0.f, 0.f};
        if (row < RTOT)      v = *(const float4*)&A[j4];
        else if (row < 136)  v = *(const float4*)&Wg[((row - RTOT) << 12) + d];
        bf4pack p;
        p.h[0] = __float2bfloat16(v.x); p.h[1] = __float2bfloat16(v.y);
        p.h[2] = __float2bfloat16(v.z); p.h[3] = __float2bfloat16(v.w);
        *(ushort4*)&AG[j4] = p.u;
    } else {
        int t = (bid - 17472) * 256 + tid;             // 8 elems/thread, 8192*512 threads
        int n = t >> 9, c8 = t & 511;
        const float4* src = (const float4*)&x[((size_t)n << 12) + (c8 << 3)];
        float4 v0 = src[0], v1 = src[1];
        bf8pack p;
        p.h[0] = __float2bfloat16(v0.x); p.h[1] = __float2bfloat16(v0.y);
        p.h[2] = __float2bfloat16(v0.z); p.h[3] = __float2bfloat16(v0.w);
        p.h[4] = __float2bfloat16(v1.x); p.h[5] = __float2bfloat16(v1.y);
        p.h[6] = __float2bfloat16(v1.z); p.h[7] = __float2bfloat16(v1.w);
        *(bf16x8*)&Xcat[(size_t)n * KC + (c8 << 3)] = p.v;
    }
}

// ------- H[s][8192][144] = Xcat[:, s-chunk] @ AG^T[s-chunk] (slice per K-split, no atomics) ---
__global__ __launch_bounds__(256) void k_hgemm(const __hip_bfloat16* __restrict__ Xcat,
                                               const __hip_bfloat16* __restrict__ AG,
                                               float* __restrict__ H) {
    __shared__ __hip_bfloat16 sX[128 * 32];
    __shared__ __hip_bfloat16 sG[NG * 32];
    const int tid  = threadIdx.x;
    const int lane = tid & 63;
    const int w    = tid >> 6;          // wave handles rows w*32 .. w*32+31
    const int quad = lane >> 4;
    const int l16  = lane & 15;
    const int m0   = blockIdx.x * 128;
    const int kbeg = blockIdx.y * (IN_F / KSPLIT);   // 1024-wide K chunk

    f32x4 acc[2][9];
    for (int i = 0; i < 2; ++i)
        for (int j = 0; j < 9; ++j)
            acc[i][j] = (f32x4){0.f, 0.f, 0.f, 0.f};

    const int sr = tid >> 2;
    const int sk2 = (((tid & 3) ^ ((sr >> 1) & 3)) << 3);   // XOR chunk swizzle
    const int qq  = quad ^ ((l16 >> 1) & 3);                // reader swizzle (lane const)

    for (int kt = kbeg; kt < kbeg + IN_F / KSPLIT; kt += 32) {
        __syncthreads();
        gl_lds16(&Xcat[(size_t)(m0 + sr) * KC + kt + sk2],      &sX[tid * 8]);
        gl_lds16(&Xcat[(size_t)(m0 + 64 + sr) * KC + kt + sk2], &sX[(tid + 256) * 8]);
        gl_lds16(&AG[(size_t)sr * IN_F + kt + sk2],             &sG[tid * 8]);
        gl_lds16(&AG[(size_t)(64 + sr) * IN_F + kt + sk2],      &sG[(tid + 256) * 8]);
        if (tid < 64)
            gl_lds16(&AG[(size_t)(128 + sr) * IN_F + kt + sk2], &sG[(tid + 512) * 8]);
        __syncthreads();

        bf16x8 a[2], b[9];
#pragma unroll
        for (int ti = 0; ti < 2; ++ti)
            a[ti] = *(const bf16x8*)(&sX[(w * 32 + ti * 16 + l16) * 32 + qq * 8]);
#pragma unroll
        for (int tj = 0; tj < 9; ++tj)
            b[tj] = *(const bf16x8*)(&sG[(tj * 16 + l16) * 32 + qq * 8]);
#pragma unroll
        for (int ti = 0; ti < 2; ++ti)
#pragma unroll
            for (int tj = 0; tj < 9; ++tj)
                acc[ti][tj] = __builtin_amdgcn_mfma_f32_16x16x32_bf16(a[ti], b[tj], acc[ti][tj], 0, 0, 0);
    }

    float* Hs = &H[(size_t)blockIdx.y * NROWS * NG];
#pragma unroll
    for (int ti = 0; ti < 2; ++ti)
#pragma unroll
        for (int tj = 0; tj < 9; ++tj) {
            int col = tj * 16 + l16;
#pragma unroll
            for (int i = 0; i < 4; ++i) {
                int row = m0 + w * 32 + ti * 16 + quad * 4 + i;
                Hs[(size_t)row * NG + col] = acc[ti][tj][i];
            }
        }
}

// -------- gate softmax + slice-reduce + scaled hg into Xcat[:, 4096:] (16 thr/row) ----------
__global__ void k_gate(const float* __restrict__ H, __hip_bfloat16* __restrict__ Xcat) {
    int id = blockIdx.x * 256 + threadIdx.x;         // 8192*16 threads
    int n = id >> 4, k8 = id & 15;
    const float* hb = &H[(size_t)n * NG];
    float lg[NE] = {0.f, 0.f, 0.f, 0.f, 0.f, 0.f, 0.f, 0.f};
#pragma unroll
    for (int s = 0; s < KSPLIT; ++s) {
        const float* hs = hb + (size_t)s * NROWS * NG;
        float4 g0 = *(const float4*)&hs[128];
        float4 g1 = *(const float4*)&hs[132];
        lg[0] += g0.x; lg[1] += g0.y; lg[2] += g0.z; lg[3] += g0.w;
        lg[4] += g1.x; lg[5] += g1.y; lg[6] += g1.z; lg[7] += g1.w;
    }
    float mx = lg[0];
#pragma unroll
    for (int e = 1; e < NE; ++e) mx = fmaxf(mx, lg[e]);
    float ssum = 0.f;
#pragma unroll
    for (int e = 0; e < NE; ++e) { lg[e] = __expf(lg[e] - mx); ssum += lg[e]; }
    float inv = SCALING / ssum;
    int e = k8 >> 1;                                 // expert for this 8-col chunk
    float ge = 0.f;
#pragma unroll
    for (int e2 = 0; e2 < NE; ++e2) if (e2 == e) ge = lg[e2];
    ge *= inv;
    float hv[8] = {0.f, 0.f, 0.f, 0.f, 0.f, 0.f, 0.f, 0.f};
#pragma unroll
    for (int s = 0; s < KSPLIT; ++s) {
        const float* hs = hb + (size_t)s * NROWS * NG;
        float4 h0 = *(const float4*)&hs[k8 * 8];
        float4 h1 = *(const float4*)&hs[k8 * 8 + 4];
        hv[0] += h0.x; hv[1] += h0.y; hv[2] += h0.z; hv[3] += h0.w;
        hv[4] += h1.x; hv[5] += h1.y; hv[6] += h1.z; hv[7] += h1.w;
    }
    bf8pack p;
#pragma unroll
    for (int i = 0; i < 8; ++i) p.h[i] = __float2bfloat16(hv[i] * ge);
    *(bf16x8*)&Xcat[(size_t)n * KC + IN_F + k8 * 8] = p.v;
}

// ------ out[8192][4096] = Xcat @ Wcat^T (K=4224, BK=64, swizzled, 2-barrier loop) ----------
__global__ __launch_bounds__(256) void k_gemm(const __hip_bfloat16* __restrict__ Xcat,
                                              const __hip_bfloat16* __restrict__ Wcat,
                                              float* __restrict__ out) {
    __shared__ __hip_bfloat16 sA[128 * 64];   // 16 KB
    __shared__ __hip_bfloat16 sB[128 * 64];   // 16 KB
    const int tid  = threadIdx.x;
    const int lane = tid & 63;
    const int w    = tid >> 6;
    const int wm   = w >> 1, wn = w & 1;  // 2x2 waves, each 64x64
    const int quad = lane >> 4;
    const int l16  = lane & 15;
    const int m0   = blockIdx.y * 128;
    const int n0   = blockIdx.x * 128;

    f32x4 acc[4][4];
#pragma unroll
    for (int i = 0; i < 4; ++i)
#pragma unroll
        for (int j = 0; j < 4; ++j)
            acc[i][j] = (f32x4){0.f, 0.f, 0.f, 0.f};

    // staging: thread t -> row srow = t>>3 (+32/round), slot chunk sc = t&7.
    // fetch global chunk gc = sc ^ (srow & 7)  (row%8 invariant across 32-row rounds)
    const int srow = tid >> 3;
    const int gc   = (tid & 7) ^ (srow & 7);
    const __hip_bfloat16* gA = &Xcat[(size_t)(m0 + srow) * KC + gc * 8];
    const __hip_bfloat16* gB = &Wcat[(size_t)(n0 + srow) * KC + gc * 8];
    const int xr = l16 & 7;              // reader XOR (lane-const)

    for (int kt = 0; kt < KC; kt += 64) {
        __syncthreads();
#pragma unroll
        for (int r = 0; r < 4; ++r) {
            gl_lds16(gA + (size_t)r * 32 * KC + kt, &sA[r * 2048 + tid * 8]);
            gl_lds16(gB + (size_t)r * 32 * KC + kt, &sB[r * 2048 + tid * 8]);
        }
        __syncthreads();

#pragma unroll
        for (int ks = 0; ks < 2; ++ks) {
            bf16x8 a[4], b[4];
#pragma unroll
            for (int t = 0; t < 4; ++t) {
                int ra = wm * 64 + t * 16 + l16;
                int rb = wn * 64 + t * 16 + l16;
                int cofs = ((ks * 4 + quad) ^ xr) * 8;
                a[t] = *(const bf16x8*)(&sA[ra * 64 + cofs]);
                b[t] = *(const bf16x8*)(&sB[rb * 64 + cofs]);
            }
#pragma unroll
            for (int ti = 0; ti < 4; ++ti)
#pragma unroll
                for (int tj = 0; tj < 4; ++tj)
                    acc[ti][tj] = __builtin_amdgcn_mfma_f32_16x16x32_bf16(a[ti], b[tj], acc[ti][tj], 0, 0, 0);
        }
    }

#pragma unroll
    for (int ti = 0; ti < 4; ++ti)
#pragma unroll
        for (int tj = 0; tj < 4; ++tj) {
            int col = n0 + wn * 64 + tj * 16 + l16;
#pragma unroll
            for (int i = 0; i < 4; ++i) {
                int row = m0 + wm * 64 + ti * 16 + quad * 4 + i;
                out[(size_t)row * OUT_F + col] = acc[ti][tj][i];
            }
        }
}

extern "C" void kernel_launch(void* const* d_in, const int* in_sizes, int n_in,
                              void* d_out, int out_size, void* d_ws, size_t ws_size,
                              hipStream_t stream) {
    const float* x  = (const float*)d_in[0];   // [8192, 4096]
    const float* W0 = (const float*)d_in[1];   // [4096, 4096]
    const float* Wg = (const float*)d_in[2];   // [8, 4096]
    const float* A  = (const float*)d_in[3];   // [8, 16, 4096]
    const float* B  = (const float*)d_in[4];   // [8, 4096, 16]
    float* out = (float*)d_out;

    char* ws = (char*)d_ws;
    size_t off = 0;
    __hip_bfloat16* Xcat = (__hip_bfloat16*)(ws + off); off += (size_t)NROWS * KC * 2;        // 69.2 MB
    __hip_bfloat16* Wcat = (__hip_bfloat16*)(ws + off); off += (size_t)OUT_F * KC * 2;        // 34.6 MB
    __hip_bfloat16* AG   = (__hip_bfloat16*)(ws + off); off += (size_t)NG * IN_F * 2;         // 1.2 MB
    float*          H    = (float*)(ws + off);          off += (size_t)KSPLIT * NROWS * NG * 4; // 18.9 MB

    k_prep<<<PREP_GRID, 256, 0, stream>>>(W0, B, A, Wg, x, Wcat, AG, Xcat);
    k_hgemm<<<dim3(NROWS / 128, KSPLIT), 256, 0, stream>>>(Xcat, AG, H);
    k_gate<<<(NROWS * 16) / 256, 256, 0, stream>>>(H, Xcat);
    k_gemm<<<dim3(OUT_F / 128, NROWS / 128), 256, 0, stream>>>(Xcat, Wcat, out);
}